// Round 3
// baseline (16.694 us; speedup 1.0000x reference)
//
#include <hip/hip_runtime.h>

#define DT_F 0.01f
#define BUFLEN 102

// searchsorted(side='left') + clip(1,7) + lerp, matching _interp_lut exactly.
__device__ __forceinline__ float interp_lut8(float x,
                                             const float* __restrict__ xp,
                                             const float* __restrict__ fp) {
    float xc = fminf(fmaxf(x, xp[0]), xp[7]);
    int idx = 0;
#pragma unroll
    for (int i = 0; i < 8; ++i) idx += (xp[i] < xc) ? 1 : 0;  // count strictly-less == searchsorted left
    idx = min(max(idx, 1), 7);
    float x0 = xp[idx - 1], x1 = xp[idx];
    float f0 = fp[idx - 1], f1 = fp[idx];
    float t = (xc - x0) / (x1 - x0 + 1e-12f);
    return f0 + t * (f1 - f0);
}

// Identical to the R1 kernel (1 elem/thread, best config so far).
__global__ void PamDelayModel_kernel(const float* __restrict__ target,
                                     const float* __restrict__ buffer,
                                     const float* __restrict__ current,
                                     const float* __restrict__ tau_p,
                                     const float* __restrict__ tau_v,
                                     const float* __restrict__ dead_p,
                                     const float* __restrict__ dead_v,
                                     const int* __restrict__ wp_ptr,
                                     float* __restrict__ out,
                                     int n_elems) {
    int i = blockIdx.x * blockDim.x + threadIdx.x;
    if (i >= n_elems) return;

    int wp = *wp_ptr;
    float tp  = target[i];
    float cur = current[i];

    float L   = interp_lut8(tp, dead_p, dead_v);
    float tau = interp_lut8(tp, tau_p, tau_v);

    float D  = fminf(fmaxf(L / DT_F, 0.0f), (float)(BUFLEN - 2));
    float ri = fmodf((float)wp - D, (float)BUFLEN);
    if (ri < 0.0f) ri += (float)BUFLEN;
    int idx0 = (int)floorf(ri);
    if (idx0 >= BUFLEN) idx0 -= BUFLEN;
    int idx1 = idx0 + 1;
    if (idx1 >= BUFLEN) idx1 -= BUFLEN;
    float alpha = ri - (float)idx0;

    const float* row = buffer + (size_t)i * BUFLEN;
    float v0 = (idx0 == wp) ? tp : row[idx0];
    float v1 = (idx1 == wp) ? tp : row[idx1];
    float delayed = (1.0f - alpha) * v0 + alpha * v1;

    float af = DT_F / (tau + DT_F);
    out[i] = (1.0f - af) * cur + af * delayed;
}

extern "C" void kernel_launch(void* const* d_in, const int* in_sizes, int n_in,
                              void* d_out, int out_size, void* d_ws, size_t ws_size,
                              hipStream_t stream) {
    const float* target  = (const float*)d_in[0];
    const float* buffer  = (const float*)d_in[1];
    const float* current = (const float*)d_in[2];
    const float* tau_p   = (const float*)d_in[3];
    const float* tau_v   = (const float*)d_in[4];
    const float* dead_p  = (const float*)d_in[5];
    const float* dead_v  = (const float*)d_in[6];
    const int*   wp_ptr  = (const int*)d_in[7];
    float* out = (float*)d_out;

    int n = out_size;  // 16384 * 16
    int block = 256;
    int grid = (n + block - 1) / block;
    // EXPERIMENT: two identical, idempotent dispatches to separate
    // per-dispatch overhead from true kernel time.
    //   T2 = 2*T_kernel + overhead;  R1 gave T1 = T_kernel + overhead = 10.8us
    PamDelayModel_kernel<<<grid, block, 0, stream>>>(
        target, buffer, current, tau_p, tau_v, dead_p, dead_v, wp_ptr, out, n);
    PamDelayModel_kernel<<<grid, block, 0, stream>>>(
        target, buffer, current, tau_p, tau_v, dead_p, dead_v, wp_ptr, out, n);
}

// Round 4
// 10.466 us; speedup vs baseline: 1.5950x; 1.5950x over previous
//
#include <hip/hip_runtime.h>

#define DT_F 0.01f
#define BUFLEN 102

// searchsorted(side='left') + clip(1,7) + lerp, matching _interp_lut exactly.
__device__ __forceinline__ float interp_lut8(float x,
                                             const float* __restrict__ xp,
                                             const float* __restrict__ fp) {
    float xc = fminf(fmaxf(x, xp[0]), xp[7]);
    int idx = 0;
#pragma unroll
    for (int i = 0; i < 8; ++i) idx += (xp[i] < xc) ? 1 : 0;  // count strictly-less == searchsorted left
    idx = min(max(idx, 1), 7);
    float x0 = xp[idx - 1], x1 = xp[idx];
    float f0 = fp[idx - 1], f1 = fp[idx];
    float t = (xc - x0) / (x1 - x0 + 1e-12f);
    return f0 + t * (f1 - f0);
}

// Final form: 1 elem/thread, single dispatch.
// R2 showed 4 elem/thread is neutral-to-worse (TLP/MLP tradeoff is a wash);
// R3's two-dispatch experiment isolated: kernel ~5.85us (~= 38MB line-granularity
// traffic at ~6.9 TB/s achievable), fixed replay overhead ~5.0us.
__global__ void PamDelayModel_kernel(const float* __restrict__ target,
                                     const float* __restrict__ buffer,
                                     const float* __restrict__ current,
                                     const float* __restrict__ tau_p,
                                     const float* __restrict__ tau_v,
                                     const float* __restrict__ dead_p,
                                     const float* __restrict__ dead_v,
                                     const int* __restrict__ wp_ptr,
                                     float* __restrict__ out,
                                     int n_elems) {
    int i = blockIdx.x * blockDim.x + threadIdx.x;
    if (i >= n_elems) return;

    int wp = *wp_ptr;
    float tp  = target[i];
    float cur = current[i];

    float L   = interp_lut8(tp, dead_p, dead_v);
    float tau = interp_lut8(tp, tau_p, tau_v);

    float D  = fminf(fmaxf(L / DT_F, 0.0f), (float)(BUFLEN - 2));
    float ri = fmodf((float)wp - D, (float)BUFLEN);
    if (ri < 0.0f) ri += (float)BUFLEN;          // floor-mod, matches jnp % for |x|<102
    int idx0 = (int)floorf(ri);
    if (idx0 >= BUFLEN) idx0 -= BUFLEN;          // fp edge guard
    int idx1 = idx0 + 1;
    if (idx1 >= BUFLEN) idx1 -= BUFLEN;
    float alpha = ri - (float)idx0;

    const float* row = buffer + (size_t)i * BUFLEN;
    // .at[:, :, write_ptr].set(target) is functional: substitute in read path
    float v0 = (idx0 == wp) ? tp : row[idx0];
    float v1 = (idx1 == wp) ? tp : row[idx1];
    float delayed = (1.0f - alpha) * v0 + alpha * v1;

    float af = DT_F / (tau + DT_F);
    out[i] = (1.0f - af) * cur + af * delayed;
}

extern "C" void kernel_launch(void* const* d_in, const int* in_sizes, int n_in,
                              void* d_out, int out_size, void* d_ws, size_t ws_size,
                              hipStream_t stream) {
    const float* target  = (const float*)d_in[0];
    const float* buffer  = (const float*)d_in[1];
    const float* current = (const float*)d_in[2];
    const float* tau_p   = (const float*)d_in[3];
    const float* tau_v   = (const float*)d_in[4];
    const float* dead_p  = (const float*)d_in[5];
    const float* dead_v  = (const float*)d_in[6];
    const int*   wp_ptr  = (const int*)d_in[7];
    float* out = (float*)d_out;

    int n = out_size;  // 16384 * 16
    int block = 256;
    int grid = (n + block - 1) / block;
    PamDelayModel_kernel<<<grid, block, 0, stream>>>(
        target, buffer, current, tau_p, tau_v, dead_p, dead_v, wp_ptr, out, n);
}